// Round 5
// baseline (1624.204 us; speedup 1.0000x reference)
//
#include <hip/hip_runtime.h>
#include <math.h>

#define B_Q   128
#define DIM   512
#define NCORP 500000
#define TR    128           // corpus rows per block tile
#define NCH   16            // K chunks of 32 (512/32)

typedef short short8 __attribute__((ext_vector_type(8)));
typedef float floatx4 __attribute__((ext_vector_type(4)));

__device__ __forceinline__ unsigned short bf16_rne(float x) {
    unsigned u = __float_as_uint(x);
    return (unsigned short)((u + 0x7FFFu + ((u >> 16) & 1u)) >> 16);
}
__device__ __forceinline__ short bf16s(float x) { return (short)bf16_rne(x); }

__device__ __forceinline__ void ins3(float s, int id,
                                     float& b0, float& b1, float& b2,
                                     int& i0, int& i1, int& i2) {
    if (s > b0)      { b2 = b1; i2 = i1; b1 = b0; i1 = i0; b0 = s; i0 = id; }
    else if (s > b1) { b2 = b1; i2 = i1; b1 = s;  i1 = id; }
    else if (s > b2) { b2 = s;  i2 = id; }
}

__device__ __forceinline__ void ins2(float s, int id,
                                     float& b0, float& b1, int& i0, int& i1) {
    if (s > b0)      { b1 = b0; i1 = i0; b0 = s; i0 = id; }
    else if (s > b1) { b1 = s;  i1 = id; }
}

__device__ __forceinline__ void ins8(float s, int id, float* bs, int* bi) {
#pragma unroll
    for (int j = 0; j < 8; ++j) {
        if (s > bs[j]) {
            float tf = bs[j]; int tx = bi[j];
            bs[j] = s; bi[j] = id; s = tf; id = tx;
        }
    }
}

// ---------------------------------------------------------------------------
// Kernel A: query = query_r @ W ; L2-normalize ; write
//  (a) exact qn f32 row-major  (for rescore)
//  (b) bf16 MFMA B-fragment-linear layout:
//      qfrag idx = kc*4096 + qg*512 + (g*16 + q15)*8 + e
// ---------------------------------------------------------------------------
__global__ void proj_kernel(const float* __restrict__ qr,
                            const float* __restrict__ W,
                            float* __restrict__ qn,
                            unsigned short* __restrict__ qfrag) {
    __shared__ float qrow[DIM];
    __shared__ float red[256];
    const int b = blockIdx.x;
    const int t = threadIdx.x;

    qrow[t]       = qr[b * DIM + t];
    qrow[t + 256] = qr[b * DIM + t + 256];
    __syncthreads();

    float acc0 = 0.f, acc1 = 0.f;
#pragma unroll 8
    for (int k = 0; k < DIM; ++k) {
        const float q = qrow[k];
        acc0 = fmaf(q, W[k * DIM + t],       acc0);
        acc1 = fmaf(q, W[k * DIM + t + 256], acc1);
    }

    red[t] = acc0 * acc0 + acc1 * acc1;
    __syncthreads();
    for (int s = 128; s > 0; s >>= 1) {
        if (t < s) red[t] += red[t + s];
        __syncthreads();
    }
    const float inv = 1.0f / fmaxf(sqrtf(red[0]), 1e-6f);

    const int qg = b >> 4, q15 = b & 15;
#pragma unroll
    for (int half = 0; half < 2; ++half) {
        const int d = t + half * 256;
        const float x = (half == 0 ? acc0 : acc1) * inv;
        qn[b * DIM + d] = x;
        const int kc = d >> 5, kk = d & 31, g = kk >> 3, e = kk & 7;
        qfrag[(size_t)kc * 4096 + qg * 512 + (g * 16 + q15) * 8 + e] = bf16_rne(x);
    }
}

// ---------------------------------------------------------------------------
// Kernel B: barrier-free MFMA cosine scan. Corpus fragments loaded DIRECTLY
// global->VGPR in A-fragment layout (no LDS, no __syncthreads in main loop).
// Depth-1 double-buffered chunk pipeline. Q fragments from L2.
// ---------------------------------------------------------------------------
__device__ __forceinline__ void load_chunk(const float* __restrict__ pA,
                                           const float* __restrict__ pB,
                                           const unsigned short* __restrict__ qfrag,
                                           int kc, int l,
                                           float4& a0, float4& a1,
                                           float4& b0, float4& b1,
                                           short8* Q) {
    a0 = *(const float4*)(pA + kc * 32);
    a1 = *(const float4*)(pA + kc * 32 + 4);
    b0 = *(const float4*)(pB + kc * 32);
    b1 = *(const float4*)(pB + kc * 32 + 4);
    const short8* qp = (const short8*)(qfrag + (size_t)kc * 4096);
#pragma unroll
    for (int qg = 0; qg < 8; ++qg) Q[qg] = qp[qg * 64 + l];
}

__device__ __forceinline__ void comp_chunk(const float4& a0, const float4& a1,
                                           const float4& b0, const float4& b1,
                                           const short8* Q,
                                           floatx4 acc[2][8],
                                           float& nsq0, float& nsq1) {
    nsq0 = fmaf(a0.x, a0.x, nsq0); nsq0 = fmaf(a0.y, a0.y, nsq0);
    nsq0 = fmaf(a0.z, a0.z, nsq0); nsq0 = fmaf(a0.w, a0.w, nsq0);
    nsq0 = fmaf(a1.x, a1.x, nsq0); nsq0 = fmaf(a1.y, a1.y, nsq0);
    nsq0 = fmaf(a1.z, a1.z, nsq0); nsq0 = fmaf(a1.w, a1.w, nsq0);
    nsq1 = fmaf(b0.x, b0.x, nsq1); nsq1 = fmaf(b0.y, b0.y, nsq1);
    nsq1 = fmaf(b0.z, b0.z, nsq1); nsq1 = fmaf(b0.w, b0.w, nsq1);
    nsq1 = fmaf(b1.x, b1.x, nsq1); nsq1 = fmaf(b1.y, b1.y, nsq1);
    nsq1 = fmaf(b1.z, b1.z, nsq1); nsq1 = fmaf(b1.w, b1.w, nsq1);

    short8 as, bs;
    as[0]=bf16s(a0.x); as[1]=bf16s(a0.y); as[2]=bf16s(a0.z); as[3]=bf16s(a0.w);
    as[4]=bf16s(a1.x); as[5]=bf16s(a1.y); as[6]=bf16s(a1.z); as[7]=bf16s(a1.w);
    bs[0]=bf16s(b0.x); bs[1]=bf16s(b0.y); bs[2]=bf16s(b0.z); bs[3]=bf16s(b0.w);
    bs[4]=bf16s(b1.x); bs[5]=bf16s(b1.y); bs[6]=bf16s(b1.z); bs[7]=bf16s(b1.w);

#pragma unroll
    for (int qg = 0; qg < 8; ++qg) {
        acc[0][qg] = __builtin_amdgcn_mfma_f32_16x16x32_bf16(as, Q[qg], acc[0][qg], 0, 0, 0);
        acc[1][qg] = __builtin_amdgcn_mfma_f32_16x16x32_bf16(bs, Q[qg], acc[1][qg], 0, 0, 0);
    }
}

__global__ __launch_bounds__(256, 2) void scan_direct_kernel(
        const float* __restrict__ corpus,
        const unsigned short* __restrict__ qfrag,
        float* __restrict__ cand_s,
        int*   __restrict__ cand_i,
        int nblk) {
    __shared__ __align__(16) unsigned char smem[32768];   // merge phase only

    const int t = threadIdx.x;
    const int w = t >> 6, l = t & 63;
    const int h = l >> 4;          // k-slice 0..3
    const int q15 = l & 15;

    float ts[8][2]; int ti[8][2];
#pragma unroll
    for (int qg = 0; qg < 8; ++qg) {
        ts[qg][0] = -1e30f; ts[qg][1] = -1e30f;
        ti[qg][0] = -1;     ti[qg][1] = -1;
    }

    const int ntiles = (NCORP + TR - 1) / TR;
    for (int tile = blockIdx.x; tile < ntiles; tile += nblk) {
        const int r0 = tile * TR;
        const int rowA = r0 + w * 32 + q15;
        const int rowB = rowA + 16;
        const int rAc = rowA < NCORP ? rowA : NCORP - 1;
        const int rBc = rowB < NCORP ? rowB : NCORP - 1;
        const float* pA = corpus + (size_t)rAc * DIM + h * 8;
        const float* pB = corpus + (size_t)rBc * DIM + h * 8;

        floatx4 acc[2][8];
#pragma unroll
        for (int rg = 0; rg < 2; ++rg)
#pragma unroll
            for (int qg = 0; qg < 8; ++qg)
#pragma unroll
                for (int j = 0; j < 4; ++j) acc[rg][qg][j] = 0.f;
        float nsq0 = 0.f, nsq1 = 0.f;

        float4 Aa0, Aa1, Ab0, Ab1; short8 Qa[8];
        float4 Ba0, Ba1, Bb0, Bb1; short8 Qb[8];

        load_chunk(pA, pB, qfrag, 0, l, Aa0, Aa1, Ab0, Ab1, Qa);
#pragma unroll
        for (int kc = 0; kc < NCH - 2; kc += 2) {
            load_chunk(pA, pB, qfrag, kc + 1, l, Ba0, Ba1, Bb0, Bb1, Qb);
            comp_chunk(Aa0, Aa1, Ab0, Ab1, Qa, acc, nsq0, nsq1);
            load_chunk(pA, pB, qfrag, kc + 2, l, Aa0, Aa1, Ab0, Ab1, Qa);
            comp_chunk(Ba0, Ba1, Bb0, Bb1, Qb, acc, nsq0, nsq1);
        }
        load_chunk(pA, pB, qfrag, NCH - 1, l, Ba0, Ba1, Bb0, Bb1, Qb);
        comp_chunk(Aa0, Aa1, Ab0, Ab1, Qa, acc, nsq0, nsq1);   // chunk 14
        comp_chunk(Ba0, Ba1, Bb0, Bb1, Qb, acc, nsq0, nsq1);   // chunk 15

        // full row norms: lanes l, l^16, l^32, l^48 hold the 4 k-slices
        nsq0 += __shfl_xor(nsq0, 16); nsq0 += __shfl_xor(nsq0, 32);
        nsq1 += __shfl_xor(nsq1, 16); nsq1 += __shfl_xor(nsq1, 32);
        const float inv0 = 1.0f / fmaxf(sqrtf(nsq0), 1e-6f);
        const float inv1 = 1.0f / fmaxf(sqrtf(nsq1), 1e-6f);

        // scores -> per-lane running top2 per query slot
#pragma unroll
        for (int reg = 0; reg < 4; ++reg) {
            const int m = h * 4 + reg;          // C-row within 16
            const float iva = __shfl(inv0, m, 64);
            const float ivb = __shfl(inv1, m, 64);
            const int ra = r0 + w * 32 + m;
            const int rb = ra + 16;
            if (ra < NCORP) {
#pragma unroll
                for (int qg = 0; qg < 8; ++qg)
                    ins2(acc[0][qg][reg] * iva, ra, ts[qg][0], ts[qg][1], ti[qg][0], ti[qg][1]);
            }
            if (rb < NCORP) {
#pragma unroll
                for (int qg = 0; qg < 8; ++qg)
                    ins2(acc[1][qg][reg] * ivb, rb, ts[qg][0], ts[qg][1], ti[qg][0], ti[qg][1]);
            }
        }
    }

    // block merge: 16 slots x 2 per query -> per-block top-3
    float* msc = (float*)smem;                 // [128][16][2] = 16 KB
    int*   mid = (int*)(smem + 16384);         // [128][16][2] = 16 KB
#pragma unroll
    for (int qg = 0; qg < 8; ++qg) {
        const int q = qg * 16 + q15;
        const int slot = w * 4 + h;
#pragma unroll
        for (int j = 0; j < 2; ++j) {
            msc[(q * 16 + slot) * 2 + j] = ts[qg][j];
            mid[(q * 16 + slot) * 2 + j] = ti[qg][j];
        }
    }
    __syncthreads();
    if (t < B_Q) {
        float b0 = -1e30f, b1 = -1e30f, b2 = -1e30f;
        int   i0 = -1, i1 = -1, i2 = -1;
        for (int e = 0; e < 32; ++e)
            ins3(msc[t * 32 + e], mid[t * 32 + e], b0, b1, b2, i0, i1, i2);
        const size_t base = ((size_t)blockIdx.x * B_Q + t) * 3;
        cand_s[base + 0] = b0; cand_s[base + 1] = b1; cand_s[base + 2] = b2;
        cand_i[base + 0] = i0; cand_i[base + 1] = i1; cand_i[base + 2] = i2;
    }
}

// ---------------------------------------------------------------------------
// Kernel C: merge per-block candidates -> global approx top-8 per query.
// ---------------------------------------------------------------------------
__global__ void merge_topk_kernel(const float* __restrict__ cand_s,
                                  const int*   __restrict__ cand_i,
                                  int nblk,
                                  float* __restrict__ topT_s,
                                  int*   __restrict__ topT_i) {
    __shared__ float ls[256 * 8];
    __shared__ int   li[256 * 8];
    const int q = blockIdx.x;
    const int t = threadIdx.x;

    float bs[8]; int bi[8];
#pragma unroll
    for (int j = 0; j < 8; ++j) { bs[j] = -1e30f; bi[j] = -1; }

    for (int blk = t; blk < nblk; blk += 256) {
        const size_t base = ((size_t)blk * B_Q + q) * 3;
#pragma unroll
        for (int j = 0; j < 3; ++j)
            ins8(cand_s[base + j], cand_i[base + j], bs, bi);
    }
#pragma unroll
    for (int j = 0; j < 8; ++j) { ls[t * 8 + j] = bs[j]; li[t * 8 + j] = bi[j]; }
    __syncthreads();

    for (int s = 128; s > 0; s >>= 1) {
        if (t < s) {
#pragma unroll
            for (int j = 0; j < 8; ++j)
                ins8(ls[(t + s) * 8 + j], li[(t + s) * 8 + j], bs, bi);
#pragma unroll
            for (int j = 0; j < 8; ++j) { ls[t * 8 + j] = bs[j]; li[t * 8 + j] = bi[j]; }
        }
        __syncthreads();
    }
    if (t == 0) {
#pragma unroll
        for (int j = 0; j < 8; ++j) { topT_s[q * 8 + j] = bs[j]; topT_i[q * 8 + j] = bi[j]; }
    }
}

// ---------------------------------------------------------------------------
// Kernel D: exact f32 rescore of 8 candidates per query -> top-3 -> out.
// d_out: [0..383] scores f32, [384..767] indices stored as f32 values.
// ---------------------------------------------------------------------------
__global__ void rescore_kernel(const float* __restrict__ corpus,
                               const float* __restrict__ qn,
                               const int*   __restrict__ topT_i,
                               float* __restrict__ out) {
    __shared__ float qrow[DIM];
    __shared__ float sc[8];
    const int q = blockIdx.x;
    const int t = threadIdx.x;
    const int g = t >> 5;       // candidate 0..7
    const int lane = t & 31;

    qrow[t]       = qn[q * DIM + t];
    qrow[t + 256] = qn[q * DIM + t + 256];
    __syncthreads();

    const int r = topT_i[q * 8 + g];
    float d = 0.f, n = 0.f;
    if (r >= 0) {
        const float* row = corpus + (size_t)r * DIM;
        for (int j = lane; j < DIM; j += 32) {
            const float c = row[j];
            d = fmaf(qrow[j], c, d);
            n = fmaf(c, c, n);
        }
    }
#pragma unroll
    for (int m = 16; m > 0; m >>= 1) {
        d += __shfl_xor(d, m);
        n += __shfl_xor(n, m);
    }
    if (lane == 0)
        sc[g] = (r >= 0) ? d / fmaxf(sqrtf(n), 1e-6f) : -1e30f;
    __syncthreads();

    if (t == 0) {
        float b0 = -1e30f, b1 = -1e30f, b2 = -1e30f;
        int   i0 = 0, i1 = 0, i2 = 0;
#pragma unroll
        for (int e = 0; e < 8; ++e)
            ins3(sc[e], topT_i[q * 8 + e], b0, b1, b2, i0, i1, i2);
        out[q * 3 + 0] = b0;
        out[q * 3 + 1] = b1;
        out[q * 3 + 2] = b2;
        out[B_Q * 3 + q * 3 + 0] = (float)i0;
        out[B_Q * 3 + q * 3 + 1] = (float)i1;
        out[B_Q * 3 + q * 3 + 2] = (float)i2;
    }
}

// ---------------------------------------------------------------------------
extern "C" void kernel_launch(void* const* d_in, const int* in_sizes, int n_in,
                              void* d_out, int out_size, void* d_ws, size_t ws_size,
                              hipStream_t stream) {
    const float* qr     = (const float*)d_in[0];  // [128,512]
    const float* corpus = (const float*)d_in[1];  // [500000,512]
    const float* W      = (const float*)d_in[2];  // [512,512]

    float* out = (float*)d_out;
    char*  ws  = (char*)d_ws;

    float*          qn     = (float*)ws;                      // 256 KB
    unsigned short* qfrag  = (unsigned short*)(ws + 262144);  // 128 KB
    float*          topT_s = (float*)(ws + 393216);           // 4 KB
    int*            topT_i = (int*)(ws + 397312);             // 4 KB
    const size_t head = 401408;

    const int ntiles = (NCORP + TR - 1) / TR;                 // 3907
    const size_t per_blk = (size_t)B_Q * 3 * (sizeof(float) + sizeof(int));
    int nblk = ntiles;
    const size_t avail = ws_size > head ? ws_size - head : 0;
    if ((size_t)nblk * per_blk > avail) nblk = (int)(avail / per_blk);
    if (nblk < 1) nblk = 1;

    float* cand_s = (float*)(ws + head);
    int*   cand_i = (int*)(ws + head + (size_t)nblk * B_Q * 3 * sizeof(float));

    proj_kernel<<<B_Q, 256, 0, stream>>>(qr, W, qn, qfrag);
    scan_direct_kernel<<<nblk, 256, 0, stream>>>(corpus, qfrag, cand_s, cand_i, nblk);
    merge_topk_kernel<<<B_Q, 256, 0, stream>>>(cand_s, cand_i, nblk, topT_s, topT_i);
    rescore_kernel<<<B_Q, 256, 0, stream>>>(corpus, qn, topT_i, out);
}

// Round 6
// 721.002 us; speedup vs baseline: 2.2527x; 2.2527x over previous
//
#include <hip/hip_runtime.h>
#include <math.h>

#define B_Q   128
#define DIM   512
#define NCORP 500000
#define TR    64            // corpus rows per tile
#define NCH   16            // K chunks of 32 (512/32)
#define NBLK  2048

typedef short short8 __attribute__((ext_vector_type(8)));
typedef float floatx4 __attribute__((ext_vector_type(4)));

__device__ __forceinline__ unsigned short bf16_rne(float x) {
    unsigned u = __float_as_uint(x);
    return (unsigned short)((u + 0x7FFFu + ((u >> 16) & 1u)) >> 16);
}

__device__ __forceinline__ void ins3(float s, int id,
                                     float& b0, float& b1, float& b2,
                                     int& i0, int& i1, int& i2) {
    if (s > b0)      { b2 = b1; i2 = i1; b1 = b0; i1 = i0; b0 = s; i0 = id; }
    else if (s > b1) { b2 = b1; i2 = i1; b1 = s;  i1 = id; }
    else if (s > b2) { b2 = s;  i2 = id; }
}

__device__ __forceinline__ void ins2(float s, int id,
                                     float& b0, float& b1, int& i0, int& i1) {
    if (s > b0)      { b1 = b0; i1 = i0; b0 = s; i0 = id; }
    else if (s > b1) { b1 = s;  i1 = id; }
}

__device__ __forceinline__ void ins8(float s, int id, float* bs, int* bi) {
#pragma unroll
    for (int j = 0; j < 8; ++j) {
        if (s > bs[j]) {
            float tf = bs[j]; int tx = bi[j];
            bs[j] = s; bi[j] = id; s = tf; id = tx;
        }
    }
}

// async global -> LDS, 16B per lane, linear dest (wave-uniform base + lane*16)
__device__ __forceinline__ void gload16(const float* g, float* l) {
    __builtin_amdgcn_global_load_lds(
        (const __attribute__((address_space(1))) unsigned*)g,
        (__attribute__((address_space(3))) unsigned*)l, 16, 0, 0);
}

// pack two f32 -> two bf16 (truncation) in one v_perm
__device__ __forceinline__ unsigned pack2(float hi, float lo) {
    return __builtin_amdgcn_perm(__float_as_uint(hi), __float_as_uint(lo),
                                 0x07060302u);
}

// ---------------------------------------------------------------------------
// Kernel A: query = query_r @ W ; L2-normalize ; write
//  (a) exact qn f32 row-major (for rescore)
//  (b) bf16 MFMA B-fragment-linear: idx = kc*4096 + qg*512 + (g*16+q15)*8 + e
// ---------------------------------------------------------------------------
__global__ void proj_kernel(const float* __restrict__ qr,
                            const float* __restrict__ W,
                            float* __restrict__ qn,
                            unsigned short* __restrict__ qfrag) {
    __shared__ float qrow[DIM];
    __shared__ float red[256];
    const int b = blockIdx.x;
    const int t = threadIdx.x;

    qrow[t]       = qr[b * DIM + t];
    qrow[t + 256] = qr[b * DIM + t + 256];
    __syncthreads();

    float acc0 = 0.f, acc1 = 0.f;
#pragma unroll 8
    for (int k = 0; k < DIM; ++k) {
        const float q = qrow[k];
        acc0 = fmaf(q, W[k * DIM + t],       acc0);
        acc1 = fmaf(q, W[k * DIM + t + 256], acc1);
    }

    red[t] = acc0 * acc0 + acc1 * acc1;
    __syncthreads();
    for (int s = 128; s > 0; s >>= 1) {
        if (t < s) red[t] += red[t + s];
        __syncthreads();
    }
    const float inv = 1.0f / fmaxf(sqrtf(red[0]), 1e-6f);

    const int qg = b >> 4, q15 = b & 15;
#pragma unroll
    for (int half = 0; half < 2; ++half) {
        const int d = t + half * 256;
        const float x = (half == 0 ? acc0 : acc1) * inv;
        qn[b * DIM + d] = x;
        const int kc = d >> 5, kk = d & 31, g = kk >> 3, e = kk & 7;
        qfrag[(size_t)kc * 4096 + qg * 512 + (g * 16 + q15) * 8 + e] = bf16_rne(x);
    }
}

// ---------------------------------------------------------------------------
// Kernel B: MFMA cosine scan. TR=64 rows/tile, 4 waves each own 16 rows x
// all 128 queries. Corpus: global_load_lds into 3-deep LDS ring, counted
// vmcnt(2) + raw s_barrier (prefetch survives barriers). Q from L2 each
// chunk. Norms from LDS f32 + shfl. Per-lane top2/qg -> block top-3.
// ---------------------------------------------------------------------------
__global__ __launch_bounds__(256, 3) void scan_kernel(
        const float* __restrict__ corpus,
        const unsigned short* __restrict__ qfrag,
        float* __restrict__ cand_s,
        int*   __restrict__ cand_i,
        int nblk) {
    __shared__ __align__(16) unsigned char smem[32768];
    float* As = (float*)smem;                 // ring: 3 bufs x 2048 f32 (24 KB)

    const int t = threadIdx.x;
    const int w = t >> 6, l = t & 63;
    const int h = l >> 4, q15 = l & 15;
    // staging lane constants (issue i covers LDS 16B slots (w*128+i*64)+l)
    const int srow_l = w * 16 + (l >> 3);                 // + i*8
    const int scol   = ((l & 7) ^ ((l >> 3) & 7)) * 4;    // swizzled f32 col
    // read lane constants
    const int lrow = w * 16 + q15;
    const int c0 = ((h * 2)     ^ (q15 & 7)) * 4;
    const int c1 = ((h * 2 + 1) ^ (q15 & 7)) * 4;

    float ts[8][2]; int ti[8][2];
#pragma unroll
    for (int qg = 0; qg < 8; ++qg) {
        ts[qg][0] = -1e30f; ts[qg][1] = -1e30f;
        ti[qg][0] = -1;     ti[qg][1] = -1;
    }

    const int ntiles = (NCORP + TR - 1) / TR;

    // stage cursor: runs exactly 2 chunks ahead of compute
    int stile = blockIdx.x, skc = 0;

    auto STAGE = [&](int buf) {
        if (stile < ntiles) {
            const int rb = stile * TR;
#pragma unroll
            for (int i = 0; i < 2; ++i) {
                int rg = rb + srow_l + i * 8;
                if (rg > NCORP - 1) rg = NCORP - 1;
                gload16(corpus + (size_t)rg * DIM + skc * 32 + scol,
                        As + buf * 2048 + (w * 128 + i * 64) * 4);
            }
        }
        if (++skc == NCH) { skc = 0; stile += nblk; }
    };

    // prologue: chunks 0,1 -> bufs 0,1 ; wait chunk0 (leave chunk1 flying)
    STAGE(0);
    STAGE(1);
    asm volatile("s_waitcnt vmcnt(2)" ::: "memory");
    __builtin_amdgcn_s_barrier();

    int cb = 0;
    for (int tile = blockIdx.x; tile < ntiles; tile += nblk) {
        const int r0 = tile * TR;
        floatx4 acc[8];
#pragma unroll
        for (int qg = 0; qg < 8; ++qg)
#pragma unroll
            for (int j = 0; j < 4; ++j) acc[qg][j] = 0.f;
        float nsq = 0.f;

#pragma unroll 1
        for (int kc = 0; kc < NCH; ++kc) {
            // Q fragment loads FIRST (oldest in vmcnt FIFO -> consuming them
            // never waits on the HBM stage loads issued after)
            const short8* qp = (const short8*)(qfrag + (size_t)kc * 4096);
            const short8 bq0 = qp[l],       bq1 = qp[64 + l];
            const short8 bq2 = qp[128 + l], bq3 = qp[192 + l];
            const short8 bq4 = qp[256 + l], bq5 = qp[320 + l];
            const short8 bq6 = qp[384 + l], bq7 = qp[448 + l];
            __builtin_amdgcn_sched_barrier(0);

            {   // stage chunk +2 into ring slot
                int nb = cb + 2; if (nb >= 3) nb -= 3;
                STAGE(nb);
            }
            __builtin_amdgcn_sched_barrier(0);

            // A fragment from LDS (swizzled read), f32 norm, v_perm pack
            const float* Ab = As + cb * 2048 + lrow * 32;
            const float4 f0 = *(const float4*)(Ab + c0);
            const float4 f1 = *(const float4*)(Ab + c1);
            nsq += f0.x*f0.x + f0.y*f0.y + f0.z*f0.z + f0.w*f0.w
                 + f1.x*f1.x + f1.y*f1.y + f1.z*f1.z + f1.w*f1.w;
            uint4 ap;
            ap.x = pack2(f0.y, f0.x); ap.y = pack2(f0.w, f0.z);
            ap.z = pack2(f1.y, f1.x); ap.w = pack2(f1.w, f1.z);
            const short8 a = __builtin_bit_cast(short8, ap);

            acc[0] = __builtin_amdgcn_mfma_f32_16x16x32_bf16(a, bq0, acc[0], 0, 0, 0);
            acc[1] = __builtin_amdgcn_mfma_f32_16x16x32_bf16(a, bq1, acc[1], 0, 0, 0);
            acc[2] = __builtin_amdgcn_mfma_f32_16x16x32_bf16(a, bq2, acc[2], 0, 0, 0);
            acc[3] = __builtin_amdgcn_mfma_f32_16x16x32_bf16(a, bq3, acc[3], 0, 0, 0);
            acc[4] = __builtin_amdgcn_mfma_f32_16x16x32_bf16(a, bq4, acc[4], 0, 0, 0);
            acc[5] = __builtin_amdgcn_mfma_f32_16x16x32_bf16(a, bq5, acc[5], 0, 0, 0);
            acc[6] = __builtin_amdgcn_mfma_f32_16x16x32_bf16(a, bq6, acc[6], 0, 0, 0);
            acc[7] = __builtin_amdgcn_mfma_f32_16x16x32_bf16(a, bq7, acc[7], 0, 0, 0);

            __builtin_amdgcn_sched_barrier(0);
            // counted wait: next chunk's stages must be done; chunk+2 keeps flying
            asm volatile("s_waitcnt vmcnt(2)" ::: "memory");
            __builtin_amdgcn_s_barrier();
            if (++cb == 3) cb = 0;
        }

        // row norms: lanes l, l^16, l^32 cover the 4 k-slice groups
        float n = nsq;
        n += __shfl_xor(n, 16); n += __shfl_xor(n, 32);
        const float invn = 1.0f / fmaxf(sqrtf(n), 1e-6f);

        // scores -> per-lane top2 per query group
#pragma unroll
        for (int reg = 0; reg < 4; ++reg) {
            const int m = h * 4 + reg;              // C row within 16
            const float iv = __shfl(invn, m, 64);
            const int r = r0 + w * 16 + m;
            if (r < NCORP) {
#pragma unroll
                for (int qg = 0; qg < 8; ++qg)
                    ins2(acc[qg][reg] * iv, r,
                         ts[qg][0], ts[qg][1], ti[qg][0], ti[qg][1]);
            }
        }
    }

    // block merge: 16 slots x top2 per query -> per-block top-3 (reuse smem)
    float* msc = (float*)smem;                 // [128][16][2] = 16 KB
    int*   mid = (int*)(smem + 16384);         // [128][16][2] = 16 KB
    __builtin_amdgcn_s_barrier();              // all waves past the ring phase
#pragma unroll
    for (int qg = 0; qg < 8; ++qg) {
        const int q = qg * 16 + q15;
        const int slot = w * 4 + h;
#pragma unroll
        for (int j = 0; j < 2; ++j) {
            msc[(q * 16 + slot) * 2 + j] = ts[qg][j];
            mid[(q * 16 + slot) * 2 + j] = ti[qg][j];
        }
    }
    __syncthreads();
    if (t < B_Q) {
        float b0 = -1e30f, b1 = -1e30f, b2 = -1e30f;
        int   i0 = -1, i1 = -1, i2 = -1;
        for (int e = 0; e < 32; ++e)
            ins3(msc[t * 32 + e], mid[t * 32 + e], b0, b1, b2, i0, i1, i2);
        const size_t base = ((size_t)blockIdx.x * B_Q + t) * 3;
        cand_s[base + 0] = b0; cand_s[base + 1] = b1; cand_s[base + 2] = b2;
        cand_i[base + 0] = i0; cand_i[base + 1] = i1; cand_i[base + 2] = i2;
    }
}

// ---------------------------------------------------------------------------
// Kernel C: merge per-block candidates -> global approx top-8 per query.
// ---------------------------------------------------------------------------
__global__ void merge_topk_kernel(const float* __restrict__ cand_s,
                                  const int*   __restrict__ cand_i,
                                  int nblk,
                                  float* __restrict__ topT_s,
                                  int*   __restrict__ topT_i) {
    __shared__ float ls[256 * 8];
    __shared__ int   li[256 * 8];
    const int q = blockIdx.x;
    const int t = threadIdx.x;

    float bs[8]; int bi[8];
#pragma unroll
    for (int j = 0; j < 8; ++j) { bs[j] = -1e30f; bi[j] = -1; }

    for (int blk = t; blk < nblk; blk += 256) {
        const size_t base = ((size_t)blk * B_Q + q) * 3;
#pragma unroll
        for (int j = 0; j < 3; ++j)
            ins8(cand_s[base + j], cand_i[base + j], bs, bi);
    }
#pragma unroll
    for (int j = 0; j < 8; ++j) { ls[t * 8 + j] = bs[j]; li[t * 8 + j] = bi[j]; }
    __syncthreads();

    for (int s = 128; s > 0; s >>= 1) {
        if (t < s) {
#pragma unroll
            for (int j = 0; j < 8; ++j)
                ins8(ls[(t + s) * 8 + j], li[(t + s) * 8 + j], bs, bi);
#pragma unroll
            for (int j = 0; j < 8; ++j) { ls[t * 8 + j] = bs[j]; li[t * 8 + j] = bi[j]; }
        }
        __syncthreads();
    }
    if (t == 0) {
#pragma unroll
        for (int j = 0; j < 8; ++j) { topT_s[q * 8 + j] = bs[j]; topT_i[q * 8 + j] = bi[j]; }
    }
}

// ---------------------------------------------------------------------------
// Kernel D: exact f32 rescore of 8 candidates per query -> top-3 -> out.
// d_out: [0..383] scores f32, [384..767] indices stored as f32 values.
// ---------------------------------------------------------------------------
__global__ void rescore_kernel(const float* __restrict__ corpus,
                               const float* __restrict__ qn,
                               const int*   __restrict__ topT_i,
                               float* __restrict__ out) {
    __shared__ float qrow[DIM];
    __shared__ float sc[8];
    const int q = blockIdx.x;
    const int t = threadIdx.x;
    const int g = t >> 5;       // candidate 0..7
    const int lane = t & 31;

    qrow[t]       = qn[q * DIM + t];
    qrow[t + 256] = qn[q * DIM + t + 256];
    __syncthreads();

    const int r = topT_i[q * 8 + g];
    float d = 0.f, n = 0.f;
    if (r >= 0) {
        const float* row = corpus + (size_t)r * DIM;
        for (int j = lane; j < DIM; j += 32) {
            const float c = row[j];
            d = fmaf(qrow[j], c, d);
            n = fmaf(c, c, n);
        }
    }
#pragma unroll
    for (int m = 16; m > 0; m >>= 1) {
        d += __shfl_xor(d, m);
        n += __shfl_xor(n, m);
    }
    if (lane == 0)
        sc[g] = (r >= 0) ? d / fmaxf(sqrtf(n), 1e-6f) : -1e30f;
    __syncthreads();

    if (t == 0) {
        float b0 = -1e30f, b1 = -1e30f, b2 = -1e30f;
        int   i0 = 0, i1 = 0, i2 = 0;
#pragma unroll
        for (int e = 0; e < 8; ++e)
            ins3(sc[e], topT_i[q * 8 + e], b0, b1, b2, i0, i1, i2);
        out[q * 3 + 0] = b0;
        out[q * 3 + 1] = b1;
        out[q * 3 + 2] = b2;
        out[B_Q * 3 + q * 3 + 0] = (float)i0;
        out[B_Q * 3 + q * 3 + 1] = (float)i1;
        out[B_Q * 3 + q * 3 + 2] = (float)i2;
    }
}

// ---------------------------------------------------------------------------
extern "C" void kernel_launch(void* const* d_in, const int* in_sizes, int n_in,
                              void* d_out, int out_size, void* d_ws, size_t ws_size,
                              hipStream_t stream) {
    const float* qr     = (const float*)d_in[0];  // [128,512]
    const float* corpus = (const float*)d_in[1];  // [500000,512]
    const float* W      = (const float*)d_in[2];  // [512,512]

    float* out = (float*)d_out;
    char*  ws  = (char*)d_ws;

    float*          qn     = (float*)ws;                      // 256 KB
    unsigned short* qfrag  = (unsigned short*)(ws + 262144);  // 128 KB
    float*          topT_s = (float*)(ws + 393216);           // 4 KB
    int*            topT_i = (int*)(ws + 397312);             // 4 KB
    const size_t head = 401408;

    const int ntiles = (NCORP + TR - 1) / TR;                 // 7813
    const size_t per_blk = (size_t)B_Q * 3 * (sizeof(float) + sizeof(int));
    int nblk = NBLK < ntiles ? NBLK : ntiles;
    const size_t avail = ws_size > head ? ws_size - head : 0;
    if ((size_t)nblk * per_blk > avail) nblk = (int)(avail / per_blk);
    if (nblk < 1) nblk = 1;

    float* cand_s = (float*)(ws + head);
    int*   cand_i = (int*)(ws + head + (size_t)nblk * B_Q * 3 * sizeof(float));

    proj_kernel<<<B_Q, 256, 0, stream>>>(qr, W, qn, qfrag);
    scan_kernel<<<nblk, 256, 0, stream>>>(corpus, qfrag, cand_s, cand_i, nblk);
    merge_topk_kernel<<<B_Q, 256, 0, stream>>>(cand_s, cand_i, nblk, topT_s, topT_i);
    rescore_kernel<<<B_Q, 256, 0, stream>>>(corpus, qn, topT_i, out);
}

// Round 7
// 619.696 us; speedup vs baseline: 2.6210x; 1.1635x over previous
//
#include <hip/hip_runtime.h>
#include <math.h>

#define B_Q   128
#define DIM   512
#define NCORP 500000
#define NCH   16              // K chunks of 32 (512/32)
#define G_SCAN 256            // scan grid (1 block/CU, LDS-capped)
#define WAVES  8              // waves per scan block
#define UNITS  (NCORP / 16)   // 31250 16-row units (exact)
#define WSTRIDE (G_SCAN * WAVES)   // 2048 waves total

typedef short short8 __attribute__((ext_vector_type(8)));
typedef float floatx4 __attribute__((ext_vector_type(4)));

__device__ __forceinline__ unsigned short bf16_rne(float x) {
    unsigned u = __float_as_uint(x);
    return (unsigned short)((u + 0x7FFFu + ((u >> 16) & 1u)) >> 16);
}

// pack two f32 -> two bf16 (truncation) in one v_perm: [lo16(b), hi16(a)]
__device__ __forceinline__ unsigned pack2(float hi, float lo) {
    return __builtin_amdgcn_perm(__float_as_uint(hi), __float_as_uint(lo),
                                 0x07060302u);
}

__device__ __forceinline__ void ins3(float s, int id,
                                     float& b0, float& b1, float& b2,
                                     int& i0, int& i1, int& i2) {
    if (s > b0)      { b2 = b1; i2 = i1; b1 = b0; i1 = i0; b0 = s; i0 = id; }
    else if (s > b1) { b2 = b1; i2 = i1; b1 = s;  i1 = id; }
    else if (s > b2) { b2 = s;  i2 = id; }
}

__device__ __forceinline__ void ins2(float s, int id,
                                     float& b0, float& b1, int& i0, int& i1) {
    if (s > b0)      { b1 = b0; i1 = i0; b0 = s; i0 = id; }
    else if (s > b1) { b1 = s;  i1 = id; }
}

__device__ __forceinline__ void ins8(float s, int id, float* bs, int* bi) {
#pragma unroll
    for (int j = 0; j < 8; ++j) {
        if (s > bs[j]) {
            float tf = bs[j]; int tx = bi[j];
            bs[j] = s; bi[j] = id; s = tf; id = tx;
        }
    }
}

// ---------------------------------------------------------------------------
// Kernel A: query = query_r @ W ; L2-normalize ; write
//  (a) exact qn f32 row-major (for rescore)
//  (b) bf16 MFMA B-fragment-linear: idx = kc*4096 + qg*512 + (g*16+q15)*8 + e
// ---------------------------------------------------------------------------
__global__ void proj_kernel(const float* __restrict__ qr,
                            const float* __restrict__ W,
                            float* __restrict__ qn,
                            unsigned short* __restrict__ qfrag) {
    __shared__ float qrow[DIM];
    __shared__ float red[256];
    const int b = blockIdx.x;
    const int t = threadIdx.x;

    qrow[t]       = qr[b * DIM + t];
    qrow[t + 256] = qr[b * DIM + t + 256];
    __syncthreads();

    float acc0 = 0.f, acc1 = 0.f;
#pragma unroll 8
    for (int k = 0; k < DIM; ++k) {
        const float q = qrow[k];
        acc0 = fmaf(q, W[k * DIM + t],       acc0);
        acc1 = fmaf(q, W[k * DIM + t + 256], acc1);
    }

    red[t] = acc0 * acc0 + acc1 * acc1;
    __syncthreads();
    for (int s = 128; s > 0; s >>= 1) {
        if (t < s) red[t] += red[t + s];
        __syncthreads();
    }
    const float inv = 1.0f / fmaxf(sqrtf(red[0]), 1e-6f);

    const int qg = b >> 4, q15 = b & 15;
#pragma unroll
    for (int half = 0; half < 2; ++half) {
        const int d = t + half * 256;
        const float x = (half == 0 ? acc0 : acc1) * inv;
        qn[b * DIM + d] = x;
        const int kc = d >> 5, kk = d & 31, g = kk >> 3, e = kk & 7;
        qfrag[(size_t)kc * 4096 + qg * 512 + (g * 16 + q15) * 8 + e] = bf16_rne(x);
    }
}

// ---------------------------------------------------------------------------
// Kernel B: barrier-free MFMA cosine scan.
//  - Q (all 128 queries, bf16 frag layout) resident in 128 KB LDS, loaded once.
//  - Corpus: per-wave 8-chunk-deep register ring of global float4 loads;
//    consume chunk kc, reissue kc+8 (compiler emits counted vmcnt waits).
//  - No __syncthreads in the main loop; waves run free.
//  - Per wave: 16 corpus rows/unit x 128 queries; acc 8x floatx4.
// ---------------------------------------------------------------------------
__global__ __launch_bounds__(512, 2) void scan_kernel(
        const float* __restrict__ corpus,
        const unsigned short* __restrict__ qfrag,
        float* __restrict__ cand_s,
        int*   __restrict__ cand_i) {
    __shared__ __align__(16) unsigned short Qlds[65536];   // 128 KB

    const int t = threadIdx.x;
    const int w = t >> 6, l = t & 63;
    const int h = l >> 4, q15 = l & 15;

    // ---- stage Q into LDS once (linear 128 KB copy) ----
    {
        const uint4* src = (const uint4*)qfrag;
        uint4* dst = (uint4*)Qlds;
#pragma unroll
        for (int i = 0; i < 16; ++i)
            dst[t + 512 * i] = src[t + 512 * i];
    }
    __syncthreads();

    float ts[8][2]; int ti[8][2];
#pragma unroll
    for (int qg = 0; qg < 8; ++qg) {
        ts[qg][0] = -1e30f; ts[qg][1] = -1e30f;
        ti[qg][0] = -1;     ti[qg][1] = -1;
    }

    const int gw = blockIdx.x * WAVES + w;        // global wave id, < WSTRIDE

    // lane's pointer for unit u: corpus[(u*16 + q15)*512 + h*8]
    const float* pcur = corpus + ((size_t)gw * 16 + q15) * DIM + h * 8;

    float4 bufA[8], bufB[8];                      // 8-chunk register ring

    // prologue: chunks 0..7 of first unit
#pragma unroll
    for (int kc = 0; kc < 8; ++kc) {
        bufA[kc] = *(const float4*)(pcur + kc * 32);
        bufB[kc] = *(const float4*)(pcur + kc * 32 + 4);
    }

    for (int u = gw; u < UNITS; u += WSTRIDE) {
        int un = u + WSTRIDE; if (un > UNITS - 1) un = UNITS - 1;   // clamp prefetch
        const float* pnext = corpus + ((size_t)un * 16 + q15) * DIM + h * 8;

        floatx4 acc[8];
#pragma unroll
        for (int qg = 0; qg < 8; ++qg)
#pragma unroll
            for (int j = 0; j < 4; ++j) acc[qg][j] = 0.f;
        float nsq = 0.f;

#pragma unroll
        for (int kc = 0; kc < NCH; ++kc) {
            const int b = kc & 7;

            // Q fragments from LDS (conflict-free lane-linear b128)
            const short8* qp = (const short8*)(Qlds + kc * 4096);
            short8 bq[8];
#pragma unroll
            for (int qg = 0; qg < 8; ++qg) bq[qg] = qp[qg * 64 + l];

            // consume ring slot b (counted vmcnt wait on its 2 loads)
            const float4 f0 = bufA[b];
            const float4 f1 = bufB[b];

            // reissue slot b for stream position +8
            if (kc < 8) {
                bufA[b] = *(const float4*)(pcur + (kc + 8) * 32);
                bufB[b] = *(const float4*)(pcur + (kc + 8) * 32 + 4);
            } else {
                bufA[b] = *(const float4*)(pnext + (kc - 8) * 32);
                bufB[b] = *(const float4*)(pnext + (kc - 8) * 32 + 4);
            }

            nsq += f0.x*f0.x + f0.y*f0.y + f0.z*f0.z + f0.w*f0.w
                 + f1.x*f1.x + f1.y*f1.y + f1.z*f1.z + f1.w*f1.w;

            uint4 ap;
            ap.x = pack2(f0.y, f0.x); ap.y = pack2(f0.w, f0.z);
            ap.z = pack2(f1.y, f1.x); ap.w = pack2(f1.w, f1.z);
            const short8 a = __builtin_bit_cast(short8, ap);

            acc[0] = __builtin_amdgcn_mfma_f32_16x16x32_bf16(a, bq[0], acc[0], 0, 0, 0);
            acc[1] = __builtin_amdgcn_mfma_f32_16x16x32_bf16(a, bq[1], acc[1], 0, 0, 0);
            acc[2] = __builtin_amdgcn_mfma_f32_16x16x32_bf16(a, bq[2], acc[2], 0, 0, 0);
            acc[3] = __builtin_amdgcn_mfma_f32_16x16x32_bf16(a, bq[3], acc[3], 0, 0, 0);
            acc[4] = __builtin_amdgcn_mfma_f32_16x16x32_bf16(a, bq[4], acc[4], 0, 0, 0);
            acc[5] = __builtin_amdgcn_mfma_f32_16x16x32_bf16(a, bq[5], acc[5], 0, 0, 0);
            acc[6] = __builtin_amdgcn_mfma_f32_16x16x32_bf16(a, bq[6], acc[6], 0, 0, 0);
            acc[7] = __builtin_amdgcn_mfma_f32_16x16x32_bf16(a, bq[7], acc[7], 0, 0, 0);
        }
        pcur = pnext;

        // full row norm for row q15: reduce the 4 k-slices (lane bits 4..5)
        float n = nsq;
        n += __shfl_xor(n, 16); n += __shfl_xor(n, 32);
        const float invn = 1.0f / fmaxf(sqrtf(n), 1e-6f);

        // scores -> per-lane running top2 per query group
#pragma unroll
        for (int reg = 0; reg < 4; ++reg) {
            const int m = h * 4 + reg;            // C row within unit
            const float iv = __shfl(invn, m, 64);
            const int r = u * 16 + m;
            if (r < NCORP) {
#pragma unroll
                for (int qg = 0; qg < 8; ++qg)
                    ins2(acc[qg][reg] * iv, r,
                         ts[qg][0], ts[qg][1], ti[qg][0], ti[qg][1]);
            }
        }
    }

    // ---- block merge: 32 slots x top2 per query -> per-block top-3 ----
    __syncthreads();                              // Q no longer needed
    float* msc = (float*)Qlds;                    // [128][32][2] f32 = 32 KB
    int*   mid = (int*)(Qlds + 16384);            // byte 32768, 32 KB
#pragma unroll
    for (int qg = 0; qg < 8; ++qg) {
        const int q = qg * 16 + q15;
        const int slot = w * 4 + h;               // 0..31
#pragma unroll
        for (int j = 0; j < 2; ++j) {
            msc[(q * 32 + slot) * 2 + j] = ts[qg][j];
            mid[(q * 32 + slot) * 2 + j] = ti[qg][j];
        }
    }
    __syncthreads();
    if (t < B_Q) {
        float b0 = -1e30f, b1 = -1e30f, b2 = -1e30f;
        int   i0 = -1, i1 = -1, i2 = -1;
        for (int e = 0; e < 64; ++e)
            ins3(msc[t * 64 + e], mid[t * 64 + e], b0, b1, b2, i0, i1, i2);
        const size_t base = ((size_t)blockIdx.x * B_Q + t) * 3;
        cand_s[base + 0] = b0; cand_s[base + 1] = b1; cand_s[base + 2] = b2;
        cand_i[base + 0] = i0; cand_i[base + 1] = i1; cand_i[base + 2] = i2;
    }
}

// ---------------------------------------------------------------------------
// Kernel C: merge per-block candidates -> global approx top-8 per query.
// ---------------------------------------------------------------------------
__global__ void merge_topk_kernel(const float* __restrict__ cand_s,
                                  const int*   __restrict__ cand_i,
                                  int nblk,
                                  float* __restrict__ topT_s,
                                  int*   __restrict__ topT_i) {
    __shared__ float ls[256 * 8];
    __shared__ int   li[256 * 8];
    const int q = blockIdx.x;
    const int t = threadIdx.x;

    float bs[8]; int bi[8];
#pragma unroll
    for (int j = 0; j < 8; ++j) { bs[j] = -1e30f; bi[j] = -1; }

    for (int blk = t; blk < nblk; blk += 256) {
        const size_t base = ((size_t)blk * B_Q + q) * 3;
#pragma unroll
        for (int j = 0; j < 3; ++j)
            ins8(cand_s[base + j], cand_i[base + j], bs, bi);
    }
#pragma unroll
    for (int j = 0; j < 8; ++j) { ls[t * 8 + j] = bs[j]; li[t * 8 + j] = bi[j]; }
    __syncthreads();

    for (int s = 128; s > 0; s >>= 1) {
        if (t < s) {
#pragma unroll
            for (int j = 0; j < 8; ++j)
                ins8(ls[(t + s) * 8 + j], li[(t + s) * 8 + j], bs, bi);
#pragma unroll
            for (int j = 0; j < 8; ++j) { ls[t * 8 + j] = bs[j]; li[t * 8 + j] = bi[j]; }
        }
        __syncthreads();
    }
    if (t == 0) {
#pragma unroll
        for (int j = 0; j < 8; ++j) { topT_s[q * 8 + j] = bs[j]; topT_i[q * 8 + j] = bi[j]; }
    }
}

// ---------------------------------------------------------------------------
// Kernel D: exact f32 rescore of 8 candidates per query -> top-3 -> out.
// d_out: [0..383] scores f32, [384..767] indices stored as f32 values.
// ---------------------------------------------------------------------------
__global__ void rescore_kernel(const float* __restrict__ corpus,
                               const float* __restrict__ qn,
                               const int*   __restrict__ topT_i,
                               float* __restrict__ out) {
    __shared__ float qrow[DIM];
    __shared__ float sc[8];
    const int q = blockIdx.x;
    const int t = threadIdx.x;
    const int g = t >> 5;       // candidate 0..7
    const int lane = t & 31;

    qrow[t]       = qn[q * DIM + t];
    qrow[t + 256] = qn[q * DIM + t + 256];
    __syncthreads();

    const int r = topT_i[q * 8 + g];
    float d = 0.f, n = 0.f;
    if (r >= 0) {
        const float* row = corpus + (size_t)r * DIM;
        for (int j = lane; j < DIM; j += 32) {
            const float c = row[j];
            d = fmaf(qrow[j], c, d);
            n = fmaf(c, c, n);
        }
    }
#pragma unroll
    for (int m = 16; m > 0; m >>= 1) {
        d += __shfl_xor(d, m);
        n += __shfl_xor(n, m);
    }
    if (lane == 0)
        sc[g] = (r >= 0) ? d / fmaxf(sqrtf(n), 1e-6f) : -1e30f;
    __syncthreads();

    if (t == 0) {
        float b0 = -1e30f, b1 = -1e30f, b2 = -1e30f;
        int   i0 = 0, i1 = 0, i2 = 0;
#pragma unroll
        for (int e = 0; e < 8; ++e)
            ins3(sc[e], topT_i[q * 8 + e], b0, b1, b2, i0, i1, i2);
        out[q * 3 + 0] = b0;
        out[q * 3 + 1] = b1;
        out[q * 3 + 2] = b2;
        out[B_Q * 3 + q * 3 + 0] = (float)i0;
        out[B_Q * 3 + q * 3 + 1] = (float)i1;
        out[B_Q * 3 + q * 3 + 2] = (float)i2;
    }
}

// ---------------------------------------------------------------------------
extern "C" void kernel_launch(void* const* d_in, const int* in_sizes, int n_in,
                              void* d_out, int out_size, void* d_ws, size_t ws_size,
                              hipStream_t stream) {
    const float* qr     = (const float*)d_in[0];  // [128,512]
    const float* corpus = (const float*)d_in[1];  // [500000,512]
    const float* W      = (const float*)d_in[2];  // [512,512]

    float* out = (float*)d_out;
    char*  ws  = (char*)d_ws;

    float*          qn     = (float*)ws;                      // 256 KB
    unsigned short* qfrag  = (unsigned short*)(ws + 262144);  // 128 KB
    float*          topT_s = (float*)(ws + 393216);           // 4 KB
    int*            topT_i = (int*)(ws + 397312);             // 4 KB
    const size_t head = 401408;

    float* cand_s = (float*)(ws + head);                      // 256*128*3 f32
    int*   cand_i = (int*)(ws + head + (size_t)G_SCAN * B_Q * 3 * sizeof(float));

    proj_kernel<<<B_Q, 256, 0, stream>>>(qr, W, qn, qfrag);
    scan_kernel<<<G_SCAN, 512, 0, stream>>>(corpus, qfrag, cand_s, cand_i);
    merge_topk_kernel<<<B_Q, 256, 0, stream>>>(cand_s, cand_i, G_SCAN, topT_s, topT_i);
    rescore_kernel<<<B_Q, 256, 0, stream>>>(corpus, qn, topT_i, out);
}